// Round 11
// baseline (1908.396 us; speedup 1.0000x reference)
//
#include <hip/hip_runtime.h>

typedef _Float16 half8 __attribute__((ext_vector_type(8)));
typedef _Float16 half4 __attribute__((ext_vector_type(4)));
typedef _Float16 half2v __attribute__((ext_vector_type(2)));
typedef float f32x4 __attribute__((ext_vector_type(4)));

#define TSIZE (1 << 19)
#define TMASK (TSIZE - 1)
#define NPAIR 4  // 4 tile-pairs = 8 tiles x 64 pts = 512 pts per block

// floor(32 * 1.3819^l) for l=0..15; every value >=0.03 from an integer.
__constant__ int c_res[16] = {32, 44, 61, 84, 116, 161, 222, 307,
                              425, 588, 812, 1123, 1551, 2144, 2963, 4095};

// Fused f32->f16 weight conversion. Segments: W1 32768, W2 262144, W3 196608 elems.
__global__ void hg_cvt_all(const float* __restrict__ W1, const float* __restrict__ W2,
                           const float* __restrict__ W3, _Float16* __restrict__ d) {
  int g = blockIdx.x * blockDim.x + threadIdx.x;  // 122880 groups of 4
  int i = g * 4;
  const float* s;
  if (i < 32768) s = W1 + i;
  else if (i < 32768 + 262144) s = W2 + (i - 32768);
  else s = W3 + (i - 32768 - 262144);
  float4 v = *(const float4*)s;
  half4 h = {(_Float16)v.x, (_Float16)v.y, (_Float16)v.z, (_Float16)v.w};
  *(half4*)(d + i) = h;
}

// Final-layer sin: deg-9 Taylor (|err|<3e-8) on |x|<=1 (clamp = identity there);
// rare outliers take the precise clamped sinf path (output is fp32).
__device__ __forceinline__ float sin_act_precise(float x) {
  if (__builtin_expect(fabsf(x) > 1.0f, 0))
    return sinf(fminf(fmaxf(x, -25.133f), 25.133f));
  float x2 = x * x;
  float p = 2.75573192e-6f;
  p = fmaf(p, x2, -1.98412698e-4f);
  p = fmaf(p, x2, 8.33333333e-3f);
  p = fmaf(p, x2, -1.66666667e-1f);
  return fmaf(p * x2, x, x);
}

// Intermediate-layer sin: med3 clamp (1 instr) + __sinf. Abs err ~1e-5 << the
// 3e-4 f16-storage rounding already applied to intermediates.
__device__ __forceinline__ float sin_act_fast(float x) {
  return __sinf(__builtin_amdgcn_fmed3f(x, -25.133f, 25.133f));
}

// LDS (padded rows, odd multiples of 16B -> <=2-way conflicts, free per m136):
// group A: X_A[64][144] @0 (9216), S_A @9216 (66560)
// group B: X_B @75776 (9216),      S_B @84992 (66560)   total 151552 B.
// Addresses reduce to base + k*64 immediates in the unrolled K-loops.
#define XROW 144
#define SROW 1040
#define XA_OFF 0
#define SA_OFF 9216
#define XB_OFF 75776
#define SB_OFF 84992
#define LD_X(xb, m, k) (*(const half8*)(&smem[(xb) + (m) * XROW + (k) * 2]))
#define LD_S(sb, m, k) (*(const half8*)(&smem[(sb) + (m) * SROW + (k) * 2]))
#define ST_S8(sb, m, n, v) \
  do { *(half4*)(&smem[(sb) + (m) * SROW + (n) * 2]) = (v); } while (0)

#define MFMA16 __builtin_amdgcn_mfma_f32_16x16x32_f16

__global__ void __launch_bounds__(1024, 4)  // 128-reg cap: 64 arch + 64 acc, R9-proven fit
hg_fused(const int* __restrict__ ybuf, const int* __restrict__ xbuf,
         const float* __restrict__ cam, const float* __restrict__ table,
         const _Float16* __restrict__ W1h, const float* __restrict__ b1,
         const _Float16* __restrict__ W2h, const float* __restrict__ b2,
         const _Float16* __restrict__ W3h, const float* __restrict__ b3,
         float* __restrict__ out) {
  __shared__ __align__(16) unsigned char smem[151552];
  const int t = threadIdx.x;
  const bool gA = (t < 512);          // wave-group: A = waves 0-7, B = waves 8-15
  const int tl = t & 511;             // thread index within group
  const int lane = tl & 63;
  const int wid = tl >> 6;            // 0..7 within group
  const int l15 = lane & 15;
  const int lhi = lane >> 4;
  const int xb = gA ? XA_OFF : XB_OFF;
  const int sb = gA ? SA_OFF : SB_OFF;
  const int blk0 = blockIdx.x << 9;   // 512 points per block
  const f32x4 vzero = {0.f, 0.f, 0.f, 0.f};

  // ---- encode one 64-pt tile -> X[xb] (R9 body, group-local) ----
  auto ENC = [&](int tile) {
    const int sub = tl & 15;
    const int res = c_res[sub];
    const float rf = (float)res;
    const unsigned strd = (unsigned)(res + 1);
    const bool dense = (res <= 723);
    const float* tb = table + ((size_t)sub * TSIZE) * 2;
    const float2 cf = ((const float2*)cam)[sub];
    const half2v hc = {(_Float16)cf.x, (_Float16)cf.y};
    const int pb = blk0 + (tile << 6);
#pragma unroll
    for (int hh = 0; hh < 2; ++hh) {
      const int m = (tl >> 4) + hh * 32;
      const int p = pb + m;
      const float u = (float)xbuf[p] / 511.0f;
      const float v = (float)ybuf[p] / 511.0f;
      const float px = u * rf, py = v * rf;
      int p0x = (int)floorf(px); p0x = p0x < 0 ? 0 : (p0x > res - 1 ? res - 1 : p0x);
      int p0y = (int)floorf(py); p0y = p0y < 0 ? 0 : (p0y > res - 1 ? res - 1 : p0y);
      const float fx = px - (float)p0x, fy = py - (float)p0y;
      const float w00 = (1.f - fx) * (1.f - fy), w10 = fx * (1.f - fy);
      const float w01 = (1.f - fx) * fy, w11 = fx * fy;
      float c0 = 0.f, c1 = 0.f;
#pragma unroll
      for (int c = 0; c < 4; ++c) {
        const unsigned cx = (unsigned)(p0x + (c & 1));
        const unsigned cy = (unsigned)(p0y + (c >> 1));
        const unsigned idx = dense ? (cx + cy * strd)
                                   : ((cx ^ (cy * 2654435761u)) & TMASK);
        const float2 f = *(const float2*)(tb + (size_t)idx * 2);
        const float w = (c == 0) ? w00 : (c == 1) ? w10 : (c == 2) ? w01 : w11;
        c0 = fmaf(w, f.x, c0);
        c1 = fmaf(w, f.y, c1);
      }
      half2v hf = {(_Float16)c0, (_Float16)c1};
      *(half2v*)(&smem[xb + m * XROW + 4 * sub]) = hf;
      *(half2v*)(&smem[xb + m * XROW + 64 + 4 * sub]) = hc;
    }
  };

  // ---- L1: sin(X @ W1^T + b1) -> S[sb] (R9 body) ----
  auto L1F = [&]() {
    const int n0 = wid << 6;
    f32x4 acc[4][4];
#pragma unroll
    for (int i = 0; i < 4; ++i)
#pragma unroll
      for (int j = 0; j < 4; ++j) acc[i][j] = vzero;
#pragma unroll
    for (int ks = 0; ks < 2; ++ks) {
      const int kk = ks * 32 + lhi * 8;
      half8 bw[4];
#pragma unroll
      for (int nf = 0; nf < 4; ++nf)
        bw[nf] = *(const half8*)(W1h + (n0 + nf * 16 + l15) * 64 + kk);
      half8 ax[4];
#pragma unroll
      for (int mf = 0; mf < 4; ++mf) ax[mf] = LD_X(xb, mf * 16 + l15, kk);
#pragma unroll
      for (int mf = 0; mf < 4; ++mf)
#pragma unroll
        for (int nf = 0; nf < 4; ++nf)
          acc[mf][nf] = MFMA16(bw[nf], ax[mf], acc[mf][nf], 0, 0, 0);
    }
#pragma unroll
    for (int nf = 0; nf < 4; ++nf) {
      const int nb = n0 + nf * 16 + lhi * 4;
      const f32x4 bb = *(const f32x4*)(b1 + nb);
#pragma unroll
      for (int mf = 0; mf < 4; ++mf) {
        half4 pk;
#pragma unroll
        for (int r = 0; r < 4; ++r)
          pk[r] = (_Float16)sin_act_fast(acc[mf][nf][r] + bb[r]);
        ST_S8(sb, mf * 16 + l15, nb, pk);
      }
    }
  };

  // ---- L2 K-loop: acc2 = sin(S @ W2^T + b2), result left in acc2 ----
  auto L2K = [&](f32x4 (&acc2)[4][4]) {
    const int n0 = wid << 6;
#pragma unroll
    for (int i = 0; i < 4; ++i)
#pragma unroll
      for (int j = 0; j < 4; ++j) acc2[i][j] = vzero;
#pragma unroll 2
    for (int ks = 0; ks < 16; ++ks) {
      const int kk = ks * 32 + lhi * 8;
      half8 bw[4];
#pragma unroll
      for (int nf = 0; nf < 4; ++nf)
        bw[nf] = *(const half8*)(W2h + (n0 + nf * 16 + l15) * 512 + kk);
      half8 ax[4];
#pragma unroll
      for (int mf = 0; mf < 4; ++mf) ax[mf] = LD_S(sb, mf * 16 + l15, kk);
#pragma unroll
      for (int mf = 0; mf < 4; ++mf)
#pragma unroll
        for (int nf = 0; nf < 4; ++nf)
          acc2[mf][nf] = MFMA16(bw[nf], ax[mf], acc2[mf][nf], 0, 0, 0);
    }
#pragma unroll
    for (int nf = 0; nf < 4; ++nf) {
      const f32x4 bb = *(const f32x4*)(b2 + (n0 + nf * 16 + lhi * 4));
#pragma unroll
      for (int mf = 0; mf < 4; ++mf)
#pragma unroll
        for (int r = 0; r < 4; ++r)
          acc2[mf][nf][r] = sin_act_fast(acc2[mf][nf][r] + bb[r]);
    }
  };

  // ---- L2 store: pack acc2 -> S[sb] in place (after the read barrier) ----
  auto L2S = [&](f32x4 (&acc2)[4][4]) {
    const int n0 = wid << 6;
#pragma unroll
    for (int nf = 0; nf < 4; ++nf) {
      const int nb = n0 + nf * 16 + lhi * 4;
#pragma unroll
      for (int mf = 0; mf < 4; ++mf) {
        half4 pk = {(_Float16)acc2[mf][nf][0], (_Float16)acc2[mf][nf][1],
                    (_Float16)acc2[mf][nf][2], (_Float16)acc2[mf][nf][3]};
        ST_S8(sb, mf * 16 + l15, nb, pk);
      }
    }
  };

  // ---- L3: sin(S @ W3^T + b3) -> out (R9 body) ----
  auto L3OUT = [&](int tile) {
    const int n0 = wid * 48;
    f32x4 acc3[4][3];
#pragma unroll
    for (int i = 0; i < 4; ++i)
#pragma unroll
      for (int j = 0; j < 3; ++j) acc3[i][j] = vzero;
#pragma unroll 2
    for (int ks = 0; ks < 16; ++ks) {
      const int kk = ks * 32 + lhi * 8;
      half8 bw[3];
#pragma unroll
      for (int nf = 0; nf < 3; ++nf)
        bw[nf] = *(const half8*)(W3h + (n0 + nf * 16 + l15) * 512 + kk);
      half8 ax[4];
#pragma unroll
      for (int mf = 0; mf < 4; ++mf) ax[mf] = LD_S(sb, mf * 16 + l15, kk);
#pragma unroll
      for (int mf = 0; mf < 4; ++mf)
#pragma unroll
        for (int nf = 0; nf < 3; ++nf)
          acc3[mf][nf] = MFMA16(bw[nf], ax[mf], acc3[mf][nf], 0, 0, 0);
    }
    const int pb = blk0 + (tile << 6);
#pragma unroll
    for (int nf = 0; nf < 3; ++nf) {
      const int nb = n0 + nf * 16 + lhi * 4;
      const f32x4 bb = *(const f32x4*)(b3 + nb);
#pragma unroll
      for (int mf = 0; mf < 4; ++mf) {
        float4 o;
        float* op = &o.x;
#pragma unroll
        for (int r = 0; r < 4; ++r)
          op[r] = sin_act_precise(acc3[mf][nf][r] + bb[r]);
        *(float4*)(out + (size_t)(pb + mf * 16 + l15) * 384 + nb) = o;
      }
    }
  };

  // =================== prologue ===================
  if (gA) ENC(0);
  __syncthreads();
  if (gA) L1F(); else ENC(1);
  __syncthreads();

  // =============== anti-phase main loop ===============
  // Every interval pairs heterogeneous phases: MFMA-heavy group vs
  // gather/VALU/store group, so both pipe classes are fed on every SIMD.
  f32x4 acc2[4][4];
  for (int k = 0; k < NPAIR; ++k) {
    // I1: A L2-K(2k) [MFMA+LDS+L2]   || B L1(2k+1) [short MFMA]
    if (gA) L2K(acc2); else L1F();
    __syncthreads();  // A done reading S_A; X_B consumed
    // I2: A S_A in-place store       || B encode(2k+3) [gathers+VALU]
    if (gA) L2S(acc2);
    else if (k < NPAIR - 1) ENC(2 * k + 3);
    __syncthreads();  // S_A final
    // I3: A L3(2k)+out [MFMA+HBM]    || B L2-K(2k+1) [MFMA+LDS+L2]
    if (gA) L3OUT(2 * k); else L2K(acc2);
    __syncthreads();  // B done reading S_B; S_A consumed
    // I4: A encode(2k+2) [gathers]   || B S_B in-place store
    if (gA) { if (k < NPAIR - 1) ENC(2 * k + 2); }
    else L2S(acc2);
    __syncthreads();  // S_B final; X_A ready
    // I5: A L1(2k+2) [short MFMA]    || B L3(2k+1)+out [MFMA+HBM]
    if (gA) { if (k < NPAIR - 1) L1F(); }
    else L3OUT(2 * k + 1);
    __syncthreads();  // S_A (L1 output) ready for next I1
  }
}

extern "C" void kernel_launch(void* const* d_in, const int* in_sizes, int n_in,
                              void* d_out, int out_size, void* d_ws, size_t ws_size,
                              hipStream_t stream) {
  const int* y = (const int*)d_in[0];
  const int* x = (const int*)d_in[1];
  const float* cam = (const float*)d_in[2];
  const float* table = (const float*)d_in[3];
  const float* W1 = (const float*)d_in[4];
  const float* b1 = (const float*)d_in[5];
  const float* W2 = (const float*)d_in[6];
  const float* b2 = (const float*)d_in[7];
  const float* W3 = (const float*)d_in[8];
  const float* b3 = (const float*)d_in[9];
  float* out = (float*)d_out;

  _Float16* Wh = (_Float16*)d_ws;      // W1h | W2h | W3h contiguous, 983040 B
  _Float16* W1h = Wh;                  // 512*64
  _Float16* W2h = W1h + 512 * 64;      // 512*512
  _Float16* W3h = W2h + 512 * 512;     // 384*512

  hg_cvt_all<<<480, 256, 0, stream>>>(W1, W2, W3, Wh);

  const int nblocks = (1 << 19) / 512;  // 1024 blocks x 8 tiles of 64 pts
  hg_fused<<<nblocks, 1024, 0, stream>>>(y, x, cam, table, W1h, b1, W2h, b2, W3h, b3, out);
}

// Round 12
// 1429.803 us; speedup vs baseline: 1.3347x; 1.3347x over previous
//
#include <hip/hip_runtime.h>

typedef _Float16 half8 __attribute__((ext_vector_type(8)));
typedef _Float16 half4 __attribute__((ext_vector_type(4)));
typedef _Float16 half2v __attribute__((ext_vector_type(2)));
typedef float f32x4 __attribute__((ext_vector_type(4)));

#define TSIZE (1 << 19)
#define TMASK (TSIZE - 1)
#define SLOT 1536  // bytes per point in d_out: 384 f32 final = holds 512 f16 intermediate

// floor(32 * 1.3819^l) for l=0..15; every value >=0.03 from an integer.
__constant__ int c_res[16] = {32, 44, 61, 84, 116, 161, 222, 307,
                              425, 588, 812, 1123, 1551, 2144, 2963, 4095};

// Fused f32->f16 weight conversion. Segments: W1 32768, W2 262144, W3 196608 elems.
__global__ void hg_cvt_all(const float* __restrict__ W1, const float* __restrict__ W2,
                           const float* __restrict__ W3, _Float16* __restrict__ d) {
  int g = blockIdx.x * blockDim.x + threadIdx.x;  // 122880 groups of 4
  int i = g * 4;
  const float* s;
  if (i < 32768) s = W1 + i;
  else if (i < 32768 + 262144) s = W2 + (i - 32768);
  else s = W3 + (i - 32768 - 262144);
  float4 v = *(const float4*)s;
  half4 h = {(_Float16)v.x, (_Float16)v.y, (_Float16)v.z, (_Float16)v.w};
  *(half4*)(d + i) = h;
}

// Final-layer sin: deg-9 Taylor (|err|<3e-8) on |x|<=1 (clamp = identity there);
// rare outliers take the precise clamped sinf path (output is fp32).
__device__ __forceinline__ float sin_act_precise(float x) {
  if (__builtin_expect(fabsf(x) > 1.0f, 0))
    return sinf(fminf(fmaxf(x, -25.133f), 25.133f));
  float x2 = x * x;
  float p = 2.75573192e-6f;
  p = fmaf(p, x2, -1.98412698e-4f);
  p = fmaf(p, x2, 8.33333333e-3f);
  p = fmaf(p, x2, -1.66666667e-1f);
  return fmaf(p * x2, x, x);
}

// Intermediate-layer sin: med3 clamp + __sinf. Abs err ~1e-5 << the 3e-4
// f16-storage rounding already applied to intermediates.
__device__ __forceinline__ float sin_act_fast(float x) {
  return __sinf(__builtin_amdgcn_fmed3f(x, -25.133f, 25.133f));
}

#define MFMA16 __builtin_amdgcn_mfma_f32_16x16x32_f16
#define XROW 144   // padded X row (64 f16 -> 144 B): odd multiple of 16 B
#define SROW 1040  // padded S row (512 f16 -> 1040 B): odd multiple of 16 B

// ============== Pass A: hashgrid encode + L1 -> H1 (f16, in d_out slots) ==============
// 128 pts/block, 1024 thr (16 waves = 2 row-halves x 8 col-groups), acc[4][4] (R4-proven).
__global__ void __launch_bounds__(1024, 4)
hg_encode_l1(const int* __restrict__ ybuf, const int* __restrict__ xbuf,
             const float* __restrict__ cam, const float* __restrict__ table,
             const _Float16* __restrict__ W1h, const float* __restrict__ b1,
             char* __restrict__ outb) {
  __shared__ __align__(16) unsigned char smem[128 * XROW];  // 18432 B
  const int t = threadIdx.x;
  const int lane = t & 63;
  const int wid = t >> 6;
  const int l15 = lane & 15;
  const int lhi = lane >> 4;
  const int rowh = wid & 1;
  const int colg = wid >> 1;
  const int mrow0 = rowh * 64;
  const int pbase = blockIdx.x << 7;  // 128 pts
  const f32x4 vzero = {0.f, 0.f, 0.f, 0.f};

  // encode 128 pts -> X_lds[128][64] f16
  {
    const int sub = t & 15;
    const int res = c_res[sub];
    const float rf = (float)res;
    const unsigned strd = (unsigned)(res + 1);
    const bool dense = (res <= 723);
    const float* tb = table + ((size_t)sub * TSIZE) * 2;
    const float2 cf = ((const float2*)cam)[sub];
    const half2v hc = {(_Float16)cf.x, (_Float16)cf.y};
#pragma unroll
    for (int hh = 0; hh < 2; ++hh) {
      const int m = (t >> 4) + hh * 64;
      const int p = pbase + m;
      const float u = (float)xbuf[p] / 511.0f;
      const float v = (float)ybuf[p] / 511.0f;
      const float px = u * rf, py = v * rf;
      int p0x = (int)floorf(px); p0x = p0x < 0 ? 0 : (p0x > res - 1 ? res - 1 : p0x);
      int p0y = (int)floorf(py); p0y = p0y < 0 ? 0 : (p0y > res - 1 ? res - 1 : p0y);
      const float fx = px - (float)p0x, fy = py - (float)p0y;
      const float w00 = (1.f - fx) * (1.f - fy), w10 = fx * (1.f - fy);
      const float w01 = (1.f - fx) * fy, w11 = fx * fy;
      float c0 = 0.f, c1 = 0.f;
#pragma unroll
      for (int c = 0; c < 4; ++c) {
        const unsigned cx = (unsigned)(p0x + (c & 1));
        const unsigned cy = (unsigned)(p0y + (c >> 1));
        const unsigned idx = dense ? (cx + cy * strd)
                                   : ((cx ^ (cy * 2654435761u)) & TMASK);
        const float2 f = *(const float2*)(tb + (size_t)idx * 2);
        const float w = (c == 0) ? w00 : (c == 1) ? w10 : (c == 2) ? w01 : w11;
        c0 = fmaf(w, f.x, c0);
        c1 = fmaf(w, f.y, c1);
      }
      half2v hf = {(_Float16)c0, (_Float16)c1};
      *(half2v*)(&smem[m * XROW + 4 * sub]) = hf;
      *(half2v*)(&smem[m * XROW + 64 + 4 * sub]) = hc;
    }
  }
  __syncthreads();

  // L1: sin(X @ W1^T + b1) -> H1 slots. mfma(A=W,B=X) => C[row=n][col=pt].
  {
    const int n0 = colg << 6;
    f32x4 acc[4][4];
#pragma unroll
    for (int i = 0; i < 4; ++i)
#pragma unroll
      for (int j = 0; j < 4; ++j) acc[i][j] = vzero;
#pragma unroll
    for (int ks = 0; ks < 2; ++ks) {
      const int kk = ks * 32 + lhi * 8;
      half8 bw[4];
#pragma unroll
      for (int nf = 0; nf < 4; ++nf)
        bw[nf] = *(const half8*)(W1h + (n0 + nf * 16 + l15) * 64 + kk);
      half8 ax[4];
#pragma unroll
      for (int mf = 0; mf < 4; ++mf)
        ax[mf] = *(const half8*)(&smem[(mrow0 + mf * 16 + l15) * XROW + kk * 2]);
#pragma unroll
      for (int mf = 0; mf < 4; ++mf)
#pragma unroll
        for (int nf = 0; nf < 4; ++nf)
          acc[mf][nf] = MFMA16(bw[nf], ax[mf], acc[mf][nf], 0, 0, 0);
    }
#pragma unroll
    for (int nf = 0; nf < 4; ++nf) {
      const int nb = n0 + nf * 16 + lhi * 4;
      const f32x4 bb = *(const f32x4*)(b1 + nb);
#pragma unroll
      for (int mf = 0; mf < 4; ++mf) {
        half4 pk;
#pragma unroll
        for (int r = 0; r < 4; ++r)
          pk[r] = (_Float16)sin_act_fast(acc[mf][nf][r] + bb[r]);
        *(half4*)(outb + (size_t)(pbase + mrow0 + mf * 16 + l15) * SLOT + nb * 2) = pk;
      }
    }
  }
}

// ============== Pass B: L2 GEMM, in-place H1 -> H2 (stage block's slots first) ==========
// 128 pts/block, 512 thr (8 waves), wave = 128 pt x 64 col, acc[8][4] = 128 AGPR.
__global__ void __launch_bounds__(512, 2)
hg_l2(const _Float16* __restrict__ W2h, const float* __restrict__ b2,
      char* __restrict__ outb) {
  __shared__ __align__(16) unsigned char smem[128 * SROW];  // 133120 B
  const int t = threadIdx.x;
  const int lane = t & 63;
  const int wid = t >> 6;  // 0..7, owns cols wid*64..+64
  const int l15 = lane & 15;
  const int lhi = lane >> 4;
  const int pbase = blockIdx.x << 7;
  const f32x4 vzero = {0.f, 0.f, 0.f, 0.f};

  // stage H1: 128 slots x 1024 B -> LDS padded rows (fully coalesced per slot)
#pragma unroll
  for (int i = 0; i < 16; ++i) {
    const int idx = i * 512 + t;
    const int p = idx >> 6;          // 0..127
    const int seg = idx & 63;        // 16B segment
    const half8 v = *(const half8*)(outb + (size_t)(pbase + p) * SLOT + seg * 16);
    *(half8*)(&smem[p * SROW + seg * 16]) = v;
  }
  __syncthreads();

  const int n0 = wid << 6;
  f32x4 acc[8][4];
#pragma unroll
  for (int i = 0; i < 8; ++i)
#pragma unroll
    for (int j = 0; j < 4; ++j) acc[i][j] = vzero;
#pragma unroll 2
  for (int ks = 0; ks < 16; ++ks) {
    const int kk = ks * 32 + lhi * 8;
    half8 bw[4];
#pragma unroll
    for (int nf = 0; nf < 4; ++nf)
      bw[nf] = *(const half8*)(W2h + (n0 + nf * 16 + l15) * 512 + kk);
#pragma unroll
    for (int mf = 0; mf < 8; ++mf) {
      const half8 ax = *(const half8*)(&smem[(mf * 16 + l15) * SROW + kk * 2]);
#pragma unroll
      for (int nf = 0; nf < 4; ++nf)
        acc[mf][nf] = MFMA16(bw[nf], ax, acc[mf][nf], 0, 0, 0);
    }
  }
  // epilogue: sin -> write back to the same slots (reads come from LDS; no barrier)
#pragma unroll
  for (int nf = 0; nf < 4; ++nf) {
    const int nb = n0 + nf * 16 + lhi * 4;
    const f32x4 bb = *(const f32x4*)(b2 + nb);
#pragma unroll
    for (int mf = 0; mf < 8; ++mf) {
      half4 pk;
#pragma unroll
      for (int r = 0; r < 4; ++r)
        pk[r] = (_Float16)sin_act_fast(acc[mf][nf][r] + bb[r]);
      *(half4*)(outb + (size_t)(pbase + mf * 16 + l15) * SLOT + nb * 2) = pk;
    }
  }
}

// ============== Pass C: L3 GEMM, in-place H2 -> final f32 out =========================
// 128 pts/block, 512 thr (8 waves), wave = 128 pt x 48 col, acc[8][3] = 96 AGPR.
__global__ void __launch_bounds__(512, 2)
hg_l3(const _Float16* __restrict__ W3h, const float* __restrict__ b3,
      char* __restrict__ outb) {
  __shared__ __align__(16) unsigned char smem[128 * SROW];  // 133120 B
  const int t = threadIdx.x;
  const int lane = t & 63;
  const int wid = t >> 6;
  const int l15 = lane & 15;
  const int lhi = lane >> 4;
  const int pbase = blockIdx.x << 7;
  const f32x4 vzero = {0.f, 0.f, 0.f, 0.f};

#pragma unroll
  for (int i = 0; i < 16; ++i) {
    const int idx = i * 512 + t;
    const int p = idx >> 6;
    const int seg = idx & 63;
    const half8 v = *(const half8*)(outb + (size_t)(pbase + p) * SLOT + seg * 16);
    *(half8*)(&smem[p * SROW + seg * 16]) = v;
  }
  __syncthreads();

  const int n0 = wid * 48;
  f32x4 acc[8][3];
#pragma unroll
  for (int i = 0; i < 8; ++i)
#pragma unroll
    for (int j = 0; j < 3; ++j) acc[i][j] = vzero;
#pragma unroll 2
  for (int ks = 0; ks < 16; ++ks) {
    const int kk = ks * 32 + lhi * 8;
    half8 bw[3];
#pragma unroll
    for (int nf = 0; nf < 3; ++nf)
      bw[nf] = *(const half8*)(W3h + (n0 + nf * 16 + l15) * 512 + kk);
#pragma unroll
    for (int mf = 0; mf < 8; ++mf) {
      const half8 ax = *(const half8*)(&smem[(mf * 16 + l15) * SROW + kk * 2]);
#pragma unroll
      for (int nf = 0; nf < 3; ++nf)
        acc[mf][nf] = MFMA16(bw[nf], ax, acc[mf][nf], 0, 0, 0);
    }
  }
  // final: precise sin -> f32 rows overwrite the slots (fully coalesced float4)
#pragma unroll
  for (int nf = 0; nf < 3; ++nf) {
    const int nb = n0 + nf * 16 + lhi * 4;
    const f32x4 bb = *(const f32x4*)(b3 + nb);
#pragma unroll
    for (int mf = 0; mf < 8; ++mf) {
      float4 o;
      float* op = &o.x;
#pragma unroll
      for (int r = 0; r < 4; ++r)
        op[r] = sin_act_precise(acc[mf][nf][r] + bb[r]);
      *(float4*)(outb + (size_t)(pbase + mf * 16 + l15) * SLOT + nb * 4) = o;
    }
  }
}

extern "C" void kernel_launch(void* const* d_in, const int* in_sizes, int n_in,
                              void* d_out, int out_size, void* d_ws, size_t ws_size,
                              hipStream_t stream) {
  const int* y = (const int*)d_in[0];
  const int* x = (const int*)d_in[1];
  const float* cam = (const float*)d_in[2];
  const float* table = (const float*)d_in[3];
  const float* W1 = (const float*)d_in[4];
  const float* b1 = (const float*)d_in[5];
  const float* W2 = (const float*)d_in[6];
  const float* b2 = (const float*)d_in[7];
  const float* W3 = (const float*)d_in[8];
  const float* b3 = (const float*)d_in[9];
  char* outb = (char*)d_out;

  _Float16* Wh = (_Float16*)d_ws;      // W1h | W2h | W3h contiguous, 983040 B
  _Float16* W1h = Wh;                  // 512*64
  _Float16* W2h = W1h + 512 * 64;      // 512*512
  _Float16* W3h = W2h + 512 * 512;     // 384*512

  hg_cvt_all<<<480, 256, 0, stream>>>(W1, W2, W3, Wh);

  const int nblocks = (1 << 19) / 128;  // 4096
  hg_encode_l1<<<nblocks, 1024, 0, stream>>>(y, x, cam, table, W1h, b1, outb);
  hg_l2<<<nblocks, 512, 0, stream>>>(W2h, b2, outb);
  hg_l3<<<nblocks, 512, 0, stream>>>(W3h, b3, outb);
}

// Round 13
// 1268.411 us; speedup vs baseline: 1.5046x; 1.1272x over previous
//
#include <hip/hip_runtime.h>

typedef _Float16 half8 __attribute__((ext_vector_type(8)));
typedef _Float16 half4 __attribute__((ext_vector_type(4)));
typedef _Float16 half2v __attribute__((ext_vector_type(2)));
typedef float f32x4 __attribute__((ext_vector_type(4)));

#define TSIZE (1 << 19)
#define TMASK (TSIZE - 1)
#define NT 8  // 8 tiles x 64 pts = 512 pts/block -> grid 1024 = 4 blocks/CU exactly

// floor(32 * 1.3819^l) for l=0..15; every value >=0.03 from an integer.
__constant__ int c_res[16] = {32, 44, 61, 84, 116, 161, 222, 307,
                              425, 588, 812, 1123, 1551, 2144, 2963, 4095};

// Fused f32->f16 weight conversion. Segments: W1 32768, W2 262144, W3 196608 elems.
__global__ void hg_cvt_all(const float* __restrict__ W1, const float* __restrict__ W2,
                           const float* __restrict__ W3, _Float16* __restrict__ d) {
  int g = blockIdx.x * blockDim.x + threadIdx.x;  // 122880 groups of 4
  int i = g * 4;
  const float* s;
  if (i < 32768) s = W1 + i;
  else if (i < 32768 + 262144) s = W2 + (i - 32768);
  else s = W3 + (i - 32768 - 262144);
  float4 v = *(const float4*)s;
  half4 h = {(_Float16)v.x, (_Float16)v.y, (_Float16)v.z, (_Float16)v.w};
  *(half4*)(d + i) = h;
}

// Final-layer sin: deg-9 Taylor (|err|<3e-8) on |x|<=1 (clamp = identity there);
// rare outliers take the precise clamped sinf path (output is fp32).
__device__ __forceinline__ float sin_act_precise(float x) {
  if (__builtin_expect(fabsf(x) > 1.0f, 0))
    return sinf(fminf(fmaxf(x, -25.133f), 25.133f));
  float x2 = x * x;
  float p = 2.75573192e-6f;
  p = fmaf(p, x2, -1.98412698e-4f);
  p = fmaf(p, x2, 8.33333333e-3f);
  p = fmaf(p, x2, -1.66666667e-1f);
  return fmaf(p * x2, x, x);
}

// Intermediate-layer sin: med3 clamp + __sinf. Abs err ~1e-5 << the 3e-4
// f16-storage rounding already applied to intermediates.
__device__ __forceinline__ float sin_act_fast(float x) {
  return __sinf(__builtin_amdgcn_fmed3f(x, -25.133f, 25.133f));
}

// LDS (padded rows, odd multiples of 16 B -> <=2-way bank conflicts, free per
// m136): X [64][144B] at 0 (9216), S [64][1040B] at 9216 (66560). Total
// 75776 B -> 2 blocks/CU (R7-proven co-residency). K-loop addresses reduce to
// base + ks*64 immediates after unroll.
#define XROW 144
#define SBASE 9216
#define SROW 1040
#define LD_X(m, k) (*(const half8*)(&smem[(m) * XROW + (k) * 2]))
#define LD_S(m, k) (*(const half8*)(&smem[SBASE + (m) * SROW + (k) * 2]))
#define ST_S8(m, n, v) \
  do { *(half4*)(&smem[SBASE + (m) * SROW + (n) * 2]) = (v); } while (0)

#define MFMA16 __builtin_amdgcn_mfma_f32_16x16x32_f16

// All barriers in this kernel guard LDS visibility only (X/S ds_writes; read
// completion is enforced by dataflow to MFMA before the barrier). Hand-rolled
// lgkm-only barrier lets global W-loads and out-stores stay IN FLIGHT across
// phases (T4 principle) — unlike __syncthreads' vmcnt(0) drain. Zero reg cost.
#define BARRIER_LGKM() asm volatile("s_waitcnt lgkmcnt(0)\n\ts_barrier" ::: "memory")

__global__ void __launch_bounds__(512, 4)  // 128-reg cap: 64 arch + 64 acc (R9-proven fit)
hg_fused(const int* __restrict__ ybuf, const int* __restrict__ xbuf,
         const float* __restrict__ cam, const float* __restrict__ table,
         const _Float16* __restrict__ W1h, const float* __restrict__ b1,
         const _Float16* __restrict__ W2h, const float* __restrict__ b2,
         const _Float16* __restrict__ W3h, const float* __restrict__ b3,
         float* __restrict__ out) {
  __shared__ __align__(16) unsigned char smem[75776];
  const int t = threadIdx.x;
  const int lane = t & 63;
  const int wid = t >> 6;   // 8 waves; wave owns 64 pts x 64 cols (48 in L3)
  const int l15 = lane & 15;
  const int lhi = lane >> 4;
  const int blk0 = blockIdx.x << 9;  // 512 pts/block
  const f32x4 vzero = {0.f, 0.f, 0.f, 0.f};

  for (int tt = 0; tt < NT; ++tt) {
    const int pbase = blk0 + (tt << 6);

    // ---------------- encode -> X_lds[64][64] f16 (R9 body) ----------------
    {
      const int sub = t & 15;
      const int res = c_res[sub];
      const float rf = (float)res;
      const unsigned strd = (unsigned)(res + 1);
      const bool dense = (res <= 723);  // (res+1)^2 <= 2^19
      const float* tb = table + ((size_t)sub * TSIZE) * 2;
      const float2 cf = ((const float2*)cam)[sub];
      const half2v hc = {(_Float16)cf.x, (_Float16)cf.y};
#pragma unroll
      for (int hh = 0; hh < 2; ++hh) {
        const int m = (t >> 4) + hh * 32;
        const int p = pbase + m;
        const float u = (float)xbuf[p] / 511.0f;
        const float v = (float)ybuf[p] / 511.0f;
        const float px = u * rf, py = v * rf;
        int p0x = (int)floorf(px); p0x = p0x < 0 ? 0 : (p0x > res - 1 ? res - 1 : p0x);
        int p0y = (int)floorf(py); p0y = p0y < 0 ? 0 : (p0y > res - 1 ? res - 1 : p0y);
        const float fx = px - (float)p0x, fy = py - (float)p0y;
        const float w00 = (1.f - fx) * (1.f - fy), w10 = fx * (1.f - fy);
        const float w01 = (1.f - fx) * fy, w11 = fx * fy;
        float c0 = 0.f, c1 = 0.f;
#pragma unroll
        for (int c = 0; c < 4; ++c) {
          const unsigned cx = (unsigned)(p0x + (c & 1));
          const unsigned cy = (unsigned)(p0y + (c >> 1));
          const unsigned idx = dense ? (cx + cy * strd)
                                     : ((cx ^ (cy * 2654435761u)) & TMASK);
          const float2 f = *(const float2*)(tb + (size_t)idx * 2);
          const float w = (c == 0) ? w00 : (c == 1) ? w10 : (c == 2) ? w01 : w11;
          c0 = fmaf(w, f.x, c0);
          c1 = fmaf(w, f.y, c1);
        }
        half2v hf = {(_Float16)c0, (_Float16)c1};
        *(half2v*)(&smem[m * XROW + 4 * sub]) = hf;
        *(half2v*)(&smem[m * XROW + 64 + 4 * sub]) = hc;
      }
    }
    BARRIER_LGKM();  // X visible; prior tile's out-stores still in flight

    // ---------------- L1: sin(X @ W1^T + b1) -> S[64,512] ----------------
    {
      const int n0 = wid << 6;
      f32x4 acc[4][4];
#pragma unroll
      for (int i = 0; i < 4; ++i)
#pragma unroll
        for (int j = 0; j < 4; ++j) acc[i][j] = vzero;
#pragma unroll
      for (int ks = 0; ks < 2; ++ks) {
        const int kk = ks * 32 + lhi * 8;
        half8 bw[4];
#pragma unroll
        for (int nf = 0; nf < 4; ++nf)
          bw[nf] = *(const half8*)(W1h + (n0 + nf * 16 + l15) * 64 + kk);
        half8 ax[4];
#pragma unroll
        for (int mf = 0; mf < 4; ++mf) ax[mf] = LD_X(mf * 16 + l15, kk);
#pragma unroll
        for (int mf = 0; mf < 4; ++mf)
#pragma unroll
          for (int nf = 0; nf < 4; ++nf)
            acc[mf][nf] = MFMA16(bw[nf], ax[mf], acc[mf][nf], 0, 0, 0);
      }
#pragma unroll
      for (int nf = 0; nf < 4; ++nf) {
        const int nb = n0 + nf * 16 + lhi * 4;
        const f32x4 bb = *(const f32x4*)(b1 + nb);
#pragma unroll
        for (int mf = 0; mf < 4; ++mf) {
          half4 pk;
#pragma unroll
          for (int r = 0; r < 4; ++r)
            pk[r] = (_Float16)sin_act_fast(acc[mf][nf][r] + bb[r]);
          ST_S8(mf * 16 + l15, nb, pk);
        }
      }
    }
    BARRIER_LGKM();  // S(h1) visible

    // ---------------- L2: sin(S @ W2^T + b2) -> S in place ----------------
    {
      const int n0 = wid << 6;
      f32x4 acc[4][4];
#pragma unroll
      for (int i = 0; i < 4; ++i)
#pragma unroll
        for (int j = 0; j < 4; ++j) acc[i][j] = vzero;
#pragma unroll 2
      for (int ks = 0; ks < 16; ++ks) {
        const int kk = ks * 32 + lhi * 8;
        half8 bw[4];
#pragma unroll
        for (int nf = 0; nf < 4; ++nf)
          bw[nf] = *(const half8*)(W2h + (n0 + nf * 16 + l15) * 512 + kk);
        half8 ax[4];
#pragma unroll
        for (int mf = 0; mf < 4; ++mf) ax[mf] = LD_S(mf * 16 + l15, kk);
#pragma unroll
        for (int mf = 0; mf < 4; ++mf)
#pragma unroll
          for (int nf = 0; nf < 4; ++nf)
            acc[mf][nf] = MFMA16(bw[nf], ax[mf], acc[mf][nf], 0, 0, 0);
      }
      // bias+sin in place in acc (zero extra registers) before the barrier
#pragma unroll
      for (int nf = 0; nf < 4; ++nf) {
        const f32x4 bb = *(const f32x4*)(b2 + (n0 + nf * 16 + lhi * 4));
#pragma unroll
        for (int mf = 0; mf < 4; ++mf)
#pragma unroll
          for (int r = 0; r < 4; ++r)
            acc[mf][nf][r] = sin_act_fast(acc[mf][nf][r] + bb[r]);
      }
      BARRIER_LGKM();  // all waves done READING S(h1) (enforced by dataflow)
#pragma unroll
      for (int nf = 0; nf < 4; ++nf) {
        const int nb = n0 + nf * 16 + lhi * 4;
#pragma unroll
        for (int mf = 0; mf < 4; ++mf) {
          half4 pk = {(_Float16)acc[mf][nf][0], (_Float16)acc[mf][nf][1],
                      (_Float16)acc[mf][nf][2], (_Float16)acc[mf][nf][3]};
          ST_S8(mf * 16 + l15, nb, pk);
        }
      }
    }
    BARRIER_LGKM();  // S(h2) visible

    // ---------------- L3: sin(S @ W3^T + b3) -> out[64,384] fp32 ----------------
    {
      const int n0 = wid * 48;
      f32x4 acc[4][3];
#pragma unroll
      for (int i = 0; i < 4; ++i)
#pragma unroll
        for (int j = 0; j < 3; ++j) acc[i][j] = vzero;
#pragma unroll 2
      for (int ks = 0; ks < 16; ++ks) {
        const int kk = ks * 32 + lhi * 8;
        half8 bw[3];
#pragma unroll
        for (int nf = 0; nf < 3; ++nf)
          bw[nf] = *(const half8*)(W3h + (n0 + nf * 16 + l15) * 512 + kk);
        half8 ax[4];
#pragma unroll
        for (int mf = 0; mf < 4; ++mf) ax[mf] = LD_S(mf * 16 + l15, kk);
#pragma unroll
        for (int mf = 0; mf < 4; ++mf)
#pragma unroll
          for (int nf = 0; nf < 3; ++nf)
            acc[mf][nf] = MFMA16(bw[nf], ax[mf], acc[mf][nf], 0, 0, 0);
      }
#pragma unroll
      for (int nf = 0; nf < 3; ++nf) {
        const int nb = n0 + nf * 16 + lhi * 4;
        const f32x4 bb = *(const f32x4*)(b3 + nb);
#pragma unroll
        for (int mf = 0; mf < 4; ++mf) {
          float4 o;
          float* op = &o.x;
#pragma unroll
          for (int r = 0; r < 4; ++r)
            op[r] = sin_act_precise(acc[mf][nf][r] + bb[r]);
          // fire-and-forget: these stores stay in flight across the next
          // tile's lgkm-only barriers (no vmcnt drain anywhere in the loop)
          *(float4*)(out + (size_t)(pbase + mf * 16 + l15) * 384 + nb) = o;
        }
      }
    }
    BARRIER_LGKM();  // L3 ds_reads done (dataflow); next tile may overwrite X/S
  }
}

extern "C" void kernel_launch(void* const* d_in, const int* in_sizes, int n_in,
                              void* d_out, int out_size, void* d_ws, size_t ws_size,
                              hipStream_t stream) {
  const int* y = (const int*)d_in[0];
  const int* x = (const int*)d_in[1];
  const float* cam = (const float*)d_in[2];
  const float* table = (const float*)d_in[3];
  const float* W1 = (const float*)d_in[4];
  const float* b1 = (const float*)d_in[5];
  const float* W2 = (const float*)d_in[6];
  const float* b2 = (const float*)d_in[7];
  const float* W3 = (const float*)d_in[8];
  const float* b3 = (const float*)d_in[9];
  float* out = (float*)d_out;

  _Float16* Wh = (_Float16*)d_ws;      // W1h | W2h | W3h contiguous, 983040 B
  _Float16* W1h = Wh;                  // 512*64
  _Float16* W2h = W1h + 512 * 64;      // 512*512
  _Float16* W3h = W2h + 512 * 512;     // 384*512

  hg_cvt_all<<<480, 256, 0, stream>>>(W1, W2, W3, Wh);

  const int nblocks = (1 << 19) / (64 * NT);  // 1024 = 4 blocks/CU exactly
  hg_fused<<<nblocks, 512, 0, stream>>>(y, x, cam, table, W1h, b1, W2h, b2, W3h, b3, out);
}